// Round 15
// baseline (557.498 us; speedup 1.0000x reference)
//
#include <hip/hip_runtime.h>
#include <hip/hip_bf16.h>
#include <math.h>

#define BB 8
#define NN 1024
#define KNNK 20
#define LDC 512

typedef __attribute__((ext_vector_type(8))) short bfrag8;
typedef __attribute__((ext_vector_type(4))) float facc4;
typedef __attribute__((ext_vector_type(2))) float v2f;

struct bh8 { __hip_bfloat16 h[8]; };

__device__ __forceinline__ bh8 cvt8(float4 a, float4 b) {
    bh8 v;
    v.h[0] = __float2bfloat16(a.x); v.h[1] = __float2bfloat16(a.y);
    v.h[2] = __float2bfloat16(a.z); v.h[3] = __float2bfloat16(a.w);
    v.h[4] = __float2bfloat16(b.x); v.h[5] = __float2bfloat16(b.y);
    v.h[6] = __float2bfloat16(b.z); v.h[7] = __float2bfloat16(b.w);
    return v;
}

// ---------------- top-20 selection, ONE query per wave: Batcher sort + head-merge ----------------
__device__ __forceinline__ void select20_one(float (*dist)[1024],
                                             unsigned char (*slotpk)[512],
                                             int q0, int w, int lane,
                                             int* __restrict__ idxout) {
    float d[16];
    int   sl[16];
#pragma unroll
    for (int j = 0; j < 16; j++) { d[j] = dist[w][lane + 64 * j]; sl[j] = j; }
    constexpr unsigned char CA[63] = {
        0,2,4,6,8,10,12,14,
        0,1,4,5,8,9,12,13,
        1,5,9,13,
        0,1,2,3,8,9,10,11,
        2,3,10,11,
        1,3,5,9,11,13,
        0,1,2,3,4,5,6,7,
        4,5,6,7,
        2,3,6,7,10,11,
        1,3,5,7,9,11,13};
    constexpr unsigned char CB[63] = {
        1,3,5,7,9,11,13,15,
        2,3,6,7,10,11,14,15,
        2,6,10,14,
        4,5,6,7,12,13,14,15,
        4,5,12,13,
        2,4,6,10,12,14,
        8,9,10,11,12,13,14,15,
        8,9,10,11,
        4,5,8,9,12,13,
        2,4,6,8,10,12,14};
#pragma unroll
    for (int c = 0; c < 63; c++) {
        const int a = CA[c], bq = CB[c];
        bool sw = d[a] < d[bq];
        float dmx = sw ? d[bq] : d[a];
        float dmn = sw ? d[a]  : d[bq];
        d[a] = dmx; d[bq] = dmn;
        int smx = sw ? sl[bq] : sl[a];
        int smn = sw ? sl[a]  : sl[bq];
        sl[a] = smx; sl[bq] = smn;
    }
#pragma unroll
    for (int j = 0; j < 16; j++) dist[w][j * 64 + lane] = d[j];
    unsigned int pk0 = 0, pk1 = 0;
#pragma unroll
    for (int j = 0; j < 8; j++) pk0 |= (unsigned)sl[j] << (4 * j);
#pragma unroll
    for (int j = 0; j < 8; j++) pk1 |= (unsigned)sl[8 + j] << (4 * j);
    *(unsigned int*)&slotpk[w][lane * 8]     = pk0;
    *(unsigned int*)&slotpk[w][lane * 8 + 4] = pk1;
    float head = d[0];
    int ptr = 0;
    for (int t = 0; t < KNNK; t++) {
        float bv = head;
#pragma unroll
        for (int s = 1; s < 64; s <<= 1) bv = fmaxf(bv, __shfl_xor(bv, s));
        unsigned long long ball = __ballot(head == bv);
        int wl = (int)__builtin_ctzll(ball);
        if (lane == wl) {
            int pp = ptr;
            int slot = (slotpk[w][lane * 8 + (pp >> 1)] >> (4 * (pp & 1))) & 15;
            idxout[(q0 + w) * KNNK + t] = slot * 64 + lane;
            pp++;
            ptr = pp;
            int a = (pp < 16 ? pp : 15) * 64 + lane;
            float nv = dist[w][a];
            head = (pp < 16) ? nv : -INFINITY;
        }
    }
}

// r1 zeroing helper
__device__ __forceinline__ void zero_r1(float* r1s, float* r1q, int O, int tid) {
    for (int i = tid; i < 32 * O; i += 256) { r1s[i] = 0.f; r1q[i] = 0.f; }
}

// ---------------- fused kNN stage 1 (C=3) + stage-1 z-gemm, 4 queries/block ----------------
__global__ __launch_bounds__(256, 6) void knn3_fused(const float* __restrict__ x,
                                                     const float* __restrict__ w1,
                                                     float* __restrict__ zf,
                                                     int* __restrict__ idxout,
                                                     float* __restrict__ r1s, float* __restrict__ r1q) {
    __shared__ float dist[4][1024];
    __shared__ __align__(8) unsigned char slotpk[4][512];
    int tid = threadIdx.x;
    int q0 = (blockIdx.x & 7) * 1024 + (blockIdx.x >> 3) * 4;   // XCD swizzle
    int b = q0 >> 10;
    if (blockIdx.x == 0) zero_r1(r1s, r1q, 64, tid);
    const float* xb = x + (size_t)b * NN * 3;
    int lane = tid & 63, w = tid >> 6;
    float qx[4], qy[4], qz[4];
#pragma unroll
    for (int q = 0; q < 4; q++) {
        const float* qr = xb + (size_t)((q0 & (NN - 1)) + q) * 3;
        qx[q] = qr[0]; qy[q] = qr[1]; qz[q] = qr[2];
    }
#pragma unroll
    for (int cq = 0; cq < 4; cq++) {
        int cand = w * 256 + cq * 64 + lane;
        const float* cr = xb + (size_t)cand * 3;
        float cx = cr[0], cy = cr[1], cz = cr[2];
        float sqc = 0.f;
        sqc += cx * cx; sqc += cy * cy; sqc += cz * cz;
#pragma unroll
        for (int q = 0; q < 4; q++) {
            float d = qx[q] * cx + qy[q] * cy + qz[q] * cz;
            dist[q][cand] = 2.f * d - sqc;
        }
    }
    // fused stage-1 z-gemm for this block's 4 queries
    for (int i = tid; i < 4 * 128; i += 256) {
        int lq = i >> 7, j = i & 127;
        const float* wr = w1 + (j < 64 ? j * 6 : (j - 64) * 6 + 3);
        const float* xr = x + (size_t)(q0 + lq) * 3;
        zf[(size_t)(q0 + lq) * 128 + j] = wr[0] * xr[0] + wr[1] * xr[1] + wr[2] * xr[2];
    }
    __syncthreads();
    select20_one(dist, slotpk, q0, w, lane, idxout);
}

// ---------------- knn core (stages 2-4), 4 queries/block, packed-fp32 + sort-select ----------------
template<int C>
__device__ __forceinline__ void knn_body(const float* __restrict__ xT,
                                         const float* __restrict__ xt, int off,
                                         const float* __restrict__ sqn,
                                         int* __restrict__ idxout,
                                         float (*dist)[1024], unsigned char (*slotpk)[512],
                                         float* qsT_raw, int knnBlk) {
    float (*qsT)[4] = (float (*)[4])qsT_raw;
    int tid = threadIdx.x;
    int q0 = (knnBlk & 7) * 1024 + (knnBlk >> 3) * 4;           // XCD swizzle
    int b = q0 >> 10;
    const float* xb = xt + (size_t)b * NN * LDC + off;
    for (int c = tid; c < C; c += 256) {
        int pb = (q0 & (NN - 1));
        float4 v;
        v.x = xb[(size_t)(pb + 0) * LDC + c];
        v.y = xb[(size_t)(pb + 1) * LDC + c];
        v.z = xb[(size_t)(pb + 2) * LDC + c];
        v.w = xb[(size_t)(pb + 3) * LDC + c];
        *(float4*)&qsT[c][0] = v;
    }
    __syncthreads();
    int lane = tid & 63, w = tid >> 6;
    int cand0 = w * 256 + 4 * lane;
    const float* xTb = xT + (size_t)b * C * 1024;
    float4 sq4 = *(const float4*)(sqn + b * NN + cand0);
    v2f acc2[4][2];          // [cand j][query-pair p]
#pragma unroll
    for (int j = 0; j < 4; j++)
#pragma unroll
        for (int p = 0; p < 2; p++) acc2[j][p] = (v2f){0.f, 0.f};
    for (int cg = 0; cg < C / 4; cg++) {
        float4 rch[4];
#pragma unroll
        for (int c = 0; c < 4; c++)
            rch[c] = *(const float4*)(xTb + (size_t)(4 * cg + c) * 1024 + cand0);
#pragma unroll
        for (int c = 0; c < 4; c++) {
            float4 qa = *(const float4*)&qsT[4 * cg + c][0];
            v2f qp[2] = {{qa.x, qa.y}, {qa.z, qa.w}};
            float rj[4] = {rch[c].x, rch[c].y, rch[c].z, rch[c].w};
#pragma unroll
            for (int j = 0; j < 4; j++) {
                v2f rr = {rj[j], rj[j]};
                acc2[j][0] += rr * qp[0];
                acc2[j][1] += rr * qp[1];
            }
        }
    }
#pragma unroll
    for (int p = 0; p < 2; p++)
#pragma unroll
        for (int half = 0; half < 2; half++) {
            int q = 2 * p + half;
            float4 dv;
            dv.x = 2.f * acc2[0][p][half] - sq4.x;
            dv.y = 2.f * acc2[1][p][half] - sq4.y;
            dv.z = 2.f * acc2[2][p][half] - sq4.z;
            dv.w = 2.f * acc2[3][p][half] - sq4.w;
            *(float4*)&dist[q][cand0] = dv;
        }
    __syncthreads();
    select20_one(dist, slotpk, q0, w, lane, idxout);
}

// ---------------- FAT kernel stages 2-3: knn (blocks<2048) + zgemm (blocks>=2048) ----------------
template<int C, int ZO2>
__global__ __launch_bounds__(256, 6) void knnz_fat(const float* __restrict__ xT,
                                                   const float* __restrict__ xt, int off,
                                                   const float* __restrict__ sqn,
                                                   int* __restrict__ idxout,
                                                   const float* __restrict__ w,
                                                   float* __restrict__ zf,
                                                   float* __restrict__ r1s, float* __restrict__ r1q,
                                                   int Onext) {
    __shared__ float dist[4][1024];
    __shared__ __align__(8) unsigned char slotpk[4][512];
    __shared__ __align__(16) float qsT_raw[C * 4];
    int tid = threadIdx.x;
    if ((int)blockIdx.x < BB * NN / 4) {
        knn_body<C>(xT, xt, off, sqn, idxout, dist, slotpk, qsT_raw, blockIdx.x);
        return;
    }
    // ---- zgemm path (xs[16][C] <= 8KB fits in dist region: 16KB) ----
    constexpr int ZO = ZO2 / 2;
    int zblk = blockIdx.x - BB * NN / 4;
    if (zblk == 0) zero_r1(r1s, r1q, Onext, tid);
    float (*xs)[C] = (float (*)[C])&dist[0][0];
    int p0 = zblk * 16;
    for (int j = tid; j < 16 * (C / 4); j += 256) {
        int p = j / (C / 4), c4 = j % (C / 4);
        *(float4*)&xs[p][4 * c4] = *(const float4*)(xt + (size_t)(p0 + p) * LDC + off + 4 * c4);
    }
    __syncthreads();
    for (int j = tid; j < ZO2; j += 256) {
        const float* wr = w + (j < ZO ? (size_t)j * 2 * C : (size_t)(j - ZO) * 2 * C + C);
        float acc[16];
#pragma unroll
        for (int p = 0; p < 16; p++) acc[p] = 0.f;
        for (int c4 = 0; c4 < C / 4; c4++) {
            float4 wv = *(const float4*)(wr + 4 * c4);
#pragma unroll
            for (int p = 0; p < 16; p++) {
                float4 xv = *(const float4*)&xs[p][4 * c4];
                acc[p] += wv.x * xv.x + wv.y * xv.y + wv.z * xv.z + wv.w * xv.w;
            }
        }
#pragma unroll
        for (int p = 0; p < 16; p++) zf[(size_t)(p0 + p) * ZO2 + j] = acc[p];
    }
}

// ---------------- stage-4 knn (separate; zeroes r1 for stage 4) ----------------
template<int C>
__global__ __launch_bounds__(256, 6) void knn_fused(const float* __restrict__ xT,
                                                    const float* __restrict__ xt, int off,
                                                    const float* __restrict__ sqn,
                                                    int* __restrict__ idxout,
                                                    float* __restrict__ r1s, float* __restrict__ r1q,
                                                    int Onext) {
    __shared__ float dist[4][1024];
    __shared__ __align__(8) unsigned char slotpk[4][512];
    __shared__ __align__(16) float qsT_raw[C * 4];
    if (blockIdx.x == 0) zero_r1(r1s, r1q, Onext, threadIdx.x);
    knn_body<C>(xT, xt, off, sqn, idxout, dist, slotpk, qsT_raw, blockIdx.x);
}

// ---------------- stage-4 z-gemm: bf16 MFMA, bf16 output ----------------
__global__ __launch_bounds__(256) void zgemm4_mfma(const float* __restrict__ xtcat,
                                                   const float* __restrict__ w4,
                                                   __hip_bfloat16* __restrict__ zf4) {
    __shared__ __hip_bfloat16 A[128][72];
    __shared__ __hip_bfloat16 W[128][72];
    int mt = blockIdx.x >> 2, nt = blockIdx.x & 3;
    int tid = threadIdx.x;
    int lane = tid & 63, wvx = tid >> 6;
    int mw = wvx >> 1, nw = wvx & 1;
    int m0 = lane & 15, qd = lane >> 4;
    int r = tid & 127, hf = tid >> 7;
    facc4 acc[4][4];
    facc4 zz = {0.f, 0.f, 0.f, 0.f};
#pragma unroll
    for (int mi = 0; mi < 4; mi++)
#pragma unroll
        for (int ni = 0; ni < 4; ni++) acc[mi][ni] = zz;
    int j = nt * 128 + r;
    const float* wsrc = w4 + (j < 256 ? (size_t)j * 256 : (size_t)(j - 256) * 256 + 128);
    const float* asrc = xtcat + (size_t)(mt * 128 + r) * 512 + 128;
    for (int kc = 0; kc < 2; kc++) {
#pragma unroll
        for (int u = 0; u < 4; u++) {
            int c0 = kc * 64 + hf * 32 + 8 * u;
            float4 a0 = *(const float4*)(asrc + c0);
            float4 a1 = *(const float4*)(asrc + c0 + 4);
            *(bh8*)&A[r][hf * 32 + 8 * u] = cvt8(a0, a1);
            float4 w0 = *(const float4*)(wsrc + c0);
            float4 w1 = *(const float4*)(wsrc + c0 + 4);
            *(bh8*)&W[r][hf * 32 + 8 * u] = cvt8(w0, w1);
        }
        __syncthreads();
#pragma unroll
        for (int kk = 0; kk < 2; kk++) {
            bfrag8 af[4], bf[4];
#pragma unroll
            for (int mi = 0; mi < 4; mi++)
                af[mi] = *(const bfrag8*)&A[64 * mw + 16 * mi + m0][32 * kk + 8 * qd];
#pragma unroll
            for (int ni = 0; ni < 4; ni++)
                bf[ni] = *(const bfrag8*)&W[64 * nw + 16 * ni + m0][32 * kk + 8 * qd];
#pragma unroll
            for (int mi = 0; mi < 4; mi++)
#pragma unroll
                for (int ni = 0; ni < 4; ni++)
                    acc[mi][ni] = __builtin_amdgcn_mfma_f32_16x16x32_bf16(af[mi], bf[ni], acc[mi][ni], 0, 0, 0);
        }
        __syncthreads();
    }
#pragma unroll
    for (int mi = 0; mi < 4; mi++)
#pragma unroll
        for (int ni = 0; ni < 4; ni++)
#pragma unroll
            for (int rg = 0; rg < 4; rg++) {
                int row = mt * 128 + mw * 64 + mi * 16 + qd * 4 + rg;
                int col = nt * 128 + nw * 64 + ni * 16 + m0;
                zf4[(size_t)row * 512 + col] = __float2bfloat16(acc[mi][ni][rg]);
            }
}

// ---------------- gather + stats (fp32 zf, stages 1-3): in-block reduce + atomics ----------------
template<int O2>
__global__ __launch_bounds__(256) void gatherstats_k(const float* __restrict__ zf,
                                                     const int* __restrict__ idx,
                                                     float* __restrict__ ymax, float* __restrict__ ymin,
                                                     float* __restrict__ r1s, float* __restrict__ r1q) {
    constexpr int O = O2 / 2;
    __shared__ float red_s[4][O], red_q[4][O];
    int wv = threadIdx.x >> 6, lane = threadIdx.x & 63;
    int n = (blockIdx.x & 7) * 1024 + (blockIdx.x >> 3) * 4 + wv;   // XCD swizzle
    int b = n >> 10;
    const float* zbatch = zf + (size_t)b * NN * O2;
    int nb[KNNK];
#pragma unroll
    for (int k = 0; k < KNNK; k++) nb[k] = idx[n * KNNK + k];
#pragma unroll
    for (int ch = 0; ch < O / 64; ch++) {
        int o = ch * 64 + lane;
        float g[KNNK];
#pragma unroll
        for (int k = 0; k < KNNK; k++) g[k] = zbatch[(size_t)nb[k] * O2 + o];
        float mx = -INFINITY, mn = INFINITY, s = 0.f, ss = 0.f;
#pragma unroll
        for (int k = 0; k < KNNK; k++) {
            float v = g[k];
            mx = fmaxf(mx, v); mn = fminf(mn, v); s += v; ss += v * v;
        }
        float zn  = zf[(size_t)n * O2 + o];
        float zbn = zf[(size_t)n * O2 + O + o];
        float d = zbn - zn;
        mx += d; mn += d;
        ss = ss + 2.f * d * s + (float)KNNK * d * d;
        s  = s + (float)KNNK * d;
        ymax[(size_t)n * O + o] = mx;
        ymin[(size_t)n * O + o] = mn;
        red_s[wv][o] = s;
        red_q[wv][o] = ss;
    }
    __syncthreads();
    int bucket = blockIdx.x & 31;
    for (int o = threadIdx.x; o < O; o += 256) {
        float s4 = red_s[0][o] + red_s[1][o] + red_s[2][o] + red_s[3][o];
        float q4 = red_q[0][o] + red_q[1][o] + red_q[2][o] + red_q[3][o];
        atomicAdd(&r1s[(size_t)bucket * O + o], s4);
        atomicAdd(&r1q[(size_t)bucket * O + o], q4);
    }
}

// ---------------- gather + stats, bf16 zf4 (stage 4) ----------------
__global__ __launch_bounds__(256) void gatherstats4_k(const __hip_bfloat16* __restrict__ zf4,
                                                      const int* __restrict__ idx,
                                                      float* __restrict__ ymax, float* __restrict__ ymin,
                                                      float* __restrict__ r1s, float* __restrict__ r1q) {
    __shared__ float red_s[4][256], red_q[4][256];
    int wv = threadIdx.x >> 6, lane = threadIdx.x & 63;
    int n = (blockIdx.x & 7) * 1024 + (blockIdx.x >> 3) * 4 + wv;
    int b = n >> 10;
    const __hip_bfloat16* zbatch = zf4 + (size_t)b * NN * 512;
    int nb[KNNK];
#pragma unroll
    for (int k = 0; k < KNNK; k++) nb[k] = idx[n * KNNK + k];
#pragma unroll
    for (int ch = 0; ch < 4; ch++) {
        int o = ch * 64 + lane;
        float g[KNNK];
#pragma unroll
        for (int k = 0; k < KNNK; k++) g[k] = __bfloat162float(zbatch[(size_t)nb[k] * 512 + o]);
        float mx = -INFINITY, mn = INFINITY, s = 0.f, ss = 0.f;
#pragma unroll
        for (int k = 0; k < KNNK; k++) {
            float v = g[k];
            mx = fmaxf(mx, v); mn = fminf(mn, v); s += v; ss += v * v;
        }
        float zn  = __bfloat162float(zf4[(size_t)n * 512 + o]);
        float zbn = __bfloat162float(zf4[(size_t)n * 512 + 256 + o]);
        float d = zbn - zn;
        mx += d; mn += d;
        ss = ss + 2.f * d * s + (float)KNNK * d * d;
        s  = s + (float)KNNK * d;
        ymax[(size_t)n * 256 + o] = mx;
        ymin[(size_t)n * 256 + o] = mn;
        red_s[wv][o] = s;
        red_q[wv][o] = ss;
    }
    __syncthreads();
    int bucket = blockIdx.x & 31;
    for (int o = threadIdx.x; o < 256; o += 256) {
        float s4 = red_s[0][o] + red_s[1][o] + red_s[2][o] + red_s[3][o];
        float q4 = red_q[0][o] + red_q[1][o] + red_q[2][o] + red_q[3][o];
        atomicAdd(&r1s[(size_t)bucket * 256 + o], s4);
        atomicAdd(&r1q[(size_t)bucket * 256 + o], q4);
    }
}

// ---------------- BN+lrelu epilogue + transpose + |c|^2 + bf16 copy, s/t computed in-block ----------------
template<int O>
__global__ __launch_bounds__(256) void epitrans2_k(const float* __restrict__ ymax, const float* __restrict__ ymin,
                                                   const float* __restrict__ r1s, const float* __restrict__ r1q,
                                                   const float* __restrict__ g, const float* __restrict__ beta,
                                                   double invM,
                                                   float* __restrict__ xtcat, int off_out,
                                                   float* __restrict__ xT, float* __restrict__ sqn,
                                                   __hip_bfloat16* __restrict__ xbf) {
    __shared__ float tile[64][O + 1];
    __shared__ float ssh[O], tth[O];
    int n0 = blockIdx.x * 64;
    int b = n0 >> 10;
    int tid = threadIdx.x;
    for (int o = tid; o < O; o += 256) {
        double sd = 0.0, qd = 0.0;
        for (int r = 0; r < 32; r++) { sd += r1s[(size_t)r * O + o]; qd += r1q[(size_t)r * O + o]; }
        double mean = sd * invM;
        double var = qd * invM - mean * mean;
        float inv = (float)(1.0 / sqrt(var + 1e-5));
        float sc = g[o] * inv;
        ssh[o] = sc;
        tth[o] = beta[o] - (float)mean * sc;
    }
    __syncthreads();
    for (int i = tid; i < 64 * O; i += 256) {
        int nl = i / O;
        int o = i & (O - 1);
        int n = n0 + nl;
        float sc = ssh[o];
        float v = sc >= 0.f ? ymax[(size_t)n * O + o] : ymin[(size_t)n * O + o];
        float y = sc * v + tth[o];
        y = y >= 0.f ? y : 0.2f * y;
        xtcat[(size_t)n * LDC + off_out + o] = y;
        xbf[(size_t)n * LDC + off_out + o] = __float2bfloat16(y);
        tile[nl][o] = y;
    }
    __syncthreads();
    if (tid < 64) {
        float sq = 0.f;
        for (int c = 0; c < O; c++) { float v = tile[tid][c]; sq += v * v; }
        sqn[n0 + tid] = sq;
    }
    int r = tid >> 4, cq = tid & 15;
#pragma unroll
    for (int ct = 0; ct < O / 16; ct++) {
        int c = ct * 16 + r;
        float4 ov;
        ov.x = tile[4 * cq + 0][c];
        ov.y = tile[4 * cq + 1][c];
        ov.z = tile[4 * cq + 2][c];
        ov.w = tile[4 * cq + 3][c];
        *(float4*)(xT + ((size_t)b * O + c) * 1024 + (n0 & (NN - 1)) + 4 * cq) = ov;
    }
}

// ---------------- stage-4 epilogue: s/t in-block, writes xbf ONLY ----------------
__global__ __launch_bounds__(256) void epilogue4_k(const float* __restrict__ ymax, const float* __restrict__ ymin,
                                                   const float* __restrict__ r1s, const float* __restrict__ r1q,
                                                   const float* __restrict__ g, const float* __restrict__ beta,
                                                   double invM,
                                                   __hip_bfloat16* __restrict__ xbf) {
    __shared__ float ssh[256], tth[256];
    int n0 = blockIdx.x * 64;
    int tid = threadIdx.x;
    {
        int o = tid;
        double sd = 0.0, qd = 0.0;
        for (int r = 0; r < 32; r++) { sd += r1s[(size_t)r * 256 + o]; qd += r1q[(size_t)r * 256 + o]; }
        double mean = sd * invM;
        double var = qd * invM - mean * mean;
        float inv = (float)(1.0 / sqrt(var + 1e-5));
        float sc = g[o] * inv;
        ssh[o] = sc;
        tth[o] = beta[o] - (float)mean * sc;
    }
    __syncthreads();
    for (int i = tid; i < 64 * 256; i += 256) {
        int nl = i >> 8;
        int o = i & 255;
        int n = n0 + nl;
        float sc = ssh[o];
        float v = sc >= 0.f ? ymax[(size_t)n * 256 + o] : ymin[(size_t)n * 256 + o];
        float y = sc * v + tth[o];
        y = y >= 0.f ? y : 0.2f * y;
        xbf[(size_t)n * LDC + 256 + o] = __float2bfloat16(y);
    }
}

// ---------------- stage 5: bf16 MFMA GEMM (W staged from fp32 w5) w/ fused stats ----------------
__global__ __launch_bounds__(256) void gemm5_mfma(const __hip_bfloat16* __restrict__ xbf,
                                                  const float* __restrict__ w5,
                                                  float* __restrict__ pmax, float* __restrict__ pmn,
                                                  float* __restrict__ ps, float* __restrict__ pq) {
    __shared__ __hip_bfloat16 A[128][72];
    __shared__ __hip_bfloat16 W[128][72];
    int mt = blockIdx.x >> 2, nt = blockIdx.x & 3;
    int tid = threadIdx.x;
    int lane = tid & 63, wvx = tid >> 6;
    int mw = wvx >> 1, nw = wvx & 1;
    int m0 = lane & 15, qd = lane >> 4;
    int r = tid & 127, hf = tid >> 7;
    facc4 acc[4][4];
    facc4 zz = {0.f, 0.f, 0.f, 0.f};
#pragma unroll
    for (int mi = 0; mi < 4; mi++)
#pragma unroll
        for (int ni = 0; ni < 4; ni++) acc[mi][ni] = zz;
    for (int kc = 0; kc < 8; kc++) {
        const __hip_bfloat16* ap = xbf + (size_t)(mt * 128 + r) * 512 + kc * 64 + hf * 32;
        const float* wp = w5 + (size_t)(nt * 128 + r) * 512 + kc * 64 + hf * 32;
#pragma unroll
        for (int u = 0; u < 4; u++) {
            bh8 av = *(const bh8*)(ap + 8 * u);
            *(bh8*)&A[r][hf * 32 + 8 * u] = av;
            float4 w0 = *(const float4*)(wp + 8 * u);
            float4 w1 = *(const float4*)(wp + 8 * u + 4);
            *(bh8*)&W[r][hf * 32 + 8 * u] = cvt8(w0, w1);
        }
        __syncthreads();
#pragma unroll
        for (int kk = 0; kk < 2; kk++) {
            bfrag8 af[4], bf[4];
#pragma unroll
            for (int mi = 0; mi < 4; mi++)
                af[mi] = *(const bfrag8*)&A[64 * mw + 16 * mi + m0][32 * kk + 8 * qd];
#pragma unroll
            for (int ni = 0; ni < 4; ni++)
                bf[ni] = *(const bfrag8*)&W[64 * nw + 16 * ni + m0][32 * kk + 8 * qd];
#pragma unroll
            for (int mi = 0; mi < 4; mi++)
#pragma unroll
                for (int ni = 0; ni < 4; ni++)
                    acc[mi][ni] = __builtin_amdgcn_mfma_f32_16x16x32_bf16(af[mi], bf[ni], acc[mi][ni], 0, 0, 0);
        }
        __syncthreads();
    }
#pragma unroll
    for (int mi = 0; mi < 4; mi++) {
        int grp = mt * 8 + mw * 4 + mi;
#pragma unroll
        for (int ni = 0; ni < 4; ni++) {
            float mx = -INFINITY, mn = INFINITY, s = 0.f, ss = 0.f;
#pragma unroll
            for (int rg = 0; rg < 4; rg++) {
                float v = acc[mi][ni][rg];
                mx = fmaxf(mx, v); mn = fminf(mn, v); s += v; ss += v * v;
            }
#pragma unroll
            for (int m = 16; m < 64; m <<= 1) {
                mx = fmaxf(mx, __shfl_xor(mx, m));
                mn = fminf(mn, __shfl_xor(mn, m));
                s += __shfl_xor(s, m);
                ss += __shfl_xor(ss, m);
            }
            if (qd == 0) {
                int o = nt * 128 + nw * 64 + ni * 16 + m0;
                pmax[(size_t)grp * 512 + o] = mx;
                pmn [(size_t)grp * 512 + o] = mn;
                ps  [(size_t)grp * 512 + o] = s;
                pq  [(size_t)grp * 512 + o] = ss;
            }
        }
    }
}

// ---------------- stage-5 BN stats (separate kernel: coalesced 8-block reduce) ----------------
__global__ __launch_bounds__(256) void bnstat5_k(const float* __restrict__ ps, const float* __restrict__ pq,
                                                 const float* __restrict__ g, const float* __restrict__ beta,
                                                 float* __restrict__ s_out, float* __restrict__ t_out) {
    __shared__ double lds_s[4][64], lds_q[4][64];
    int lane = threadIdx.x & 63, wv = threadIdx.x >> 6;
    int o = blockIdx.x * 64 + lane;
    double s = 0.0, q = 0.0;
    for (int r = wv; r < 512; r += 4) {
        s += ps[(size_t)r * 512 + o];
        q += pq[(size_t)r * 512 + o];
    }
    lds_s[wv][lane] = s; lds_q[wv][lane] = q;
    __syncthreads();
    if (wv == 0) {
        s = lds_s[0][lane] + lds_s[1][lane] + lds_s[2][lane] + lds_s[3][lane];
        q = lds_q[0][lane] + lds_q[1][lane] + lds_q[2][lane] + lds_q[3][lane];
        double invM = 1.0 / (BB * NN);
        double mean = s * invM;
        double var = q * invM - mean * mean;
        float inv = (float)(1.0 / sqrt(var + 1e-5));
        float sc = g[o] * inv;
        s_out[o] = sc;
        t_out[o] = beta[o] - (float)mean * sc;
    }
}

// ---------------- per-batch max/min reduce + BN + lrelu + feat @ wemb^T ----------------
__global__ __launch_bounds__(256) void featgemm_k(const float* __restrict__ pmax, const float* __restrict__ pmn,
                                                  const float* __restrict__ s, const float* __restrict__ t,
                                                  const float* __restrict__ wemb, float* __restrict__ out) {
    __shared__ __align__(16) float feat[512];
    int b = blockIdx.x, tid = threadIdx.x;
    for (int o = tid; o < 512; o += 256) {
        float mx = -INFINITY, mn = INFINITY;
        for (int r = b * 64; r < (b + 1) * 64; r++) {
            mx = fmaxf(mx, pmax[(size_t)r * 512 + o]);
            mn = fminf(mn, pmn [(size_t)r * 512 + o]);
        }
        float sc = s[o];
        float v = sc >= 0.f ? mx : mn;
        float y = sc * v + t[o];
        feat[o] = y >= 0.f ? y : 0.2f * y;
    }
    __syncthreads();
    const float4* wr = (const float4*)(wemb + (size_t)tid * 512);
    float acc = 0.f;
    for (int c4 = 0; c4 < 128; c4++) {
        float4 wv = wr[c4];
        float4 fv = *(const float4*)&feat[c4 * 4];
        acc += wv.x * fv.x + wv.y * fv.y + wv.z * fv.z + wv.w * fv.w;
    }
    out[(size_t)b * 256 + tid] = acc;
}

extern "C" void kernel_launch(void* const* d_in, const int* in_sizes, int n_in,
                              void* d_out, int out_size, void* d_ws, size_t ws_size,
                              hipStream_t stream) {
    const float* x    = (const float*)d_in[0];
    const float* w1   = (const float*)d_in[1];
    const float* g1   = (const float*)d_in[2];
    const float* b1   = (const float*)d_in[3];
    const float* w2   = (const float*)d_in[4];
    const float* g2   = (const float*)d_in[5];
    const float* b2   = (const float*)d_in[6];
    const float* w3   = (const float*)d_in[7];
    const float* g3   = (const float*)d_in[8];
    const float* b3   = (const float*)d_in[9];
    const float* w4   = (const float*)d_in[10];
    const float* g4   = (const float*)d_in[11];
    const float* b4   = (const float*)d_in[12];
    const float* w5   = (const float*)d_in[13];
    const float* g5   = (const float*)d_in[14];
    const float* b5   = (const float*)d_in[15];
    const float* wemb = (const float*)d_in[16];
    float* out = (float*)d_out;

    float* fws    = (float*)d_ws;
    float* xtcat  = fws;                                 // 4,194,304
    float* ymax   = xtcat + (size_t)BB * NN * 512;       // 2,097,152
    float* ymin   = ymax + (size_t)BB * NN * 256;        // 2,097,152
    float* psum   = ymin + (size_t)BB * NN * 256;        // 2,097,152 (xT alias)
    float* psumsq = psum + (size_t)BB * NN * 256;        // 2,097,152 (spare)
    float* xT     = psum;                                // alias
    float* pmax   = ymax;                                // alias: stage-5 partials
    float* pmn    = pmax + 512 * 512;
    float* ps5    = pmn + 512 * 512;
    float* pq5    = ps5 + 512 * 512;
    float* sqn    = psumsq + (size_t)BB * NN * 256;      // 8192
    float* s_arr  = sqn + BB * NN;                       // 512
    float* t_arr  = s_arr + 512;                         // 512
    float* r1s    = t_arr + 512;                         // 32*512
    float* r1q    = r1s + 32 * 512;                      // 32*512
    int*   idxb   = (int*)(r1q + 32 * 512);              // 8192*20 ints
    float* zfull  = (float*)(idxb + BB * NN * KNNK);     // 8192*512 fp32 (stages 1-3)
    __hip_bfloat16* zf4 = (__hip_bfloat16*)zfull;        // alias: stage-4 z, bf16
    __hip_bfloat16* xbf = (__hip_bfloat16*)(zfull + (size_t)BB * NN * 512);   // 8192*512 bf16

    const double invM_edge = 1.0 / ((double)BB * NN * KNNK);
    const int nbn = BB * NN;
    const int NK = nbn / 4;       // 2048 knn blocks (4 queries each)
    const int NZ = nbn / 16;      // 512 zgemm blocks

    // ---- Stage 1 ----
    knn3_fused<<<NK, 256, 0, stream>>>(x, w1, zfull, idxb, r1s, r1q);
    gatherstats_k<128><<<nbn / 4, 256, 0, stream>>>(zfull, idxb, ymax, ymin, r1s, r1q);
    epitrans2_k<64><<<128, 256, 0, stream>>>(ymax, ymin, r1s, r1q, g1, b1, invM_edge, xtcat, 0, xT, sqn, xbf);

    // ---- Stage 2 ----
    knnz_fat<64, 128><<<NK + NZ, 256, 0, stream>>>(xT, xtcat, 0, sqn, idxb, w2, zfull, r1s, r1q, 64);
    gatherstats_k<128><<<nbn / 4, 256, 0, stream>>>(zfull, idxb, ymax, ymin, r1s, r1q);
    epitrans2_k<64><<<128, 256, 0, stream>>>(ymax, ymin, r1s, r1q, g2, b2, invM_edge, xtcat, 64, xT, sqn, xbf);

    // ---- Stage 3 ----
    knnz_fat<64, 256><<<NK + NZ, 256, 0, stream>>>(xT, xtcat, 64, sqn, idxb, w3, zfull, r1s, r1q, 128);
    gatherstats_k<256><<<nbn / 4, 256, 0, stream>>>(zfull, idxb, ymax, ymin, r1s, r1q);
    epitrans2_k<128><<<128, 256, 0, stream>>>(ymax, ymin, r1s, r1q, g3, b3, invM_edge, xtcat, 128, xT, sqn, xbf);

    // ---- Stage 4 ----
    knn_fused<128><<<NK, 256, 0, stream>>>(xT, xtcat, 128, sqn, idxb, r1s, r1q, 256);
    zgemm4_mfma<<<256, 256, 0, stream>>>(xtcat, w4, zf4);
    gatherstats4_k<<<nbn / 4, 256, 0, stream>>>(zf4, idxb, ymax, ymin, r1s, r1q);
    epilogue4_k<<<128, 256, 0, stream>>>(ymax, ymin, r1s, r1q, g4, b4, invM_edge, xbf);

    // ---- Stage 5 ----
    gemm5_mfma<<<256, 256, 0, stream>>>(xbf, w5, pmax, pmn, ps5, pq5);
    bnstat5_k<<<8, 256, 0, stream>>>(ps5, pq5, g5, b5, s_arr, t_arr);
    featgemm_k<<<BB, 256, 0, stream>>>(pmax, pmn, s_arr, t_arr, wemb, out);
}

// Round 16
// 414.885 us; speedup vs baseline: 1.3437x; 1.3437x over previous
//
#include <hip/hip_runtime.h>
#include <hip/hip_bf16.h>
#include <math.h>

#define BB 8
#define NN 1024
#define KNNK 20
#define LDC 512

typedef __attribute__((ext_vector_type(8))) short bfrag8;
typedef __attribute__((ext_vector_type(4))) float facc4;
typedef __attribute__((ext_vector_type(2))) float v2f;

struct bh8 { __hip_bfloat16 h[8]; };

__device__ __forceinline__ bh8 cvt8(float4 a, float4 b) {
    bh8 v;
    v.h[0] = __float2bfloat16(a.x); v.h[1] = __float2bfloat16(a.y);
    v.h[2] = __float2bfloat16(a.z); v.h[3] = __float2bfloat16(a.w);
    v.h[4] = __float2bfloat16(b.x); v.h[5] = __float2bfloat16(b.y);
    v.h[6] = __float2bfloat16(b.z); v.h[7] = __float2bfloat16(b.w);
    return v;
}

// ---------------- top-20 selection: per-lane Batcher sort + head-merge (exact fp32) ----------------
__device__ __forceinline__ void select20_srt(float (*dist)[1024],
                                             unsigned char (*slotpk)[512],
                                             int q0, int w, int lane,
                                             int* __restrict__ idxout) {
    float d[2][16];
    int   sl[2][16];
#pragma unroll
    for (int qi = 0; qi < 2; qi++) {
        int row = w * 2 + qi;
#pragma unroll
        for (int j = 0; j < 16; j++) { d[qi][j] = dist[row][lane + 64 * j]; sl[qi][j] = j; }
    }
    constexpr unsigned char CA[63] = {
        0,2,4,6,8,10,12,14,
        0,1,4,5,8,9,12,13,
        1,5,9,13,
        0,1,2,3,8,9,10,11,
        2,3,10,11,
        1,3,5,9,11,13,
        0,1,2,3,4,5,6,7,
        4,5,6,7,
        2,3,6,7,10,11,
        1,3,5,7,9,11,13};
    constexpr unsigned char CB[63] = {
        1,3,5,7,9,11,13,15,
        2,3,6,7,10,11,14,15,
        2,6,10,14,
        4,5,6,7,12,13,14,15,
        4,5,12,13,
        2,4,6,10,12,14,
        8,9,10,11,12,13,14,15,
        8,9,10,11,
        4,5,8,9,12,13,
        2,4,6,8,10,12,14};
#pragma unroll
    for (int c = 0; c < 63; c++) {
        const int a = CA[c], bq = CB[c];
#pragma unroll
        for (int qi = 0; qi < 2; qi++) {
            bool sw = d[qi][a] < d[qi][bq];
            float dmx = sw ? d[qi][bq] : d[qi][a];
            float dmn = sw ? d[qi][a]  : d[qi][bq];
            d[qi][a] = dmx; d[qi][bq] = dmn;
            int smx = sw ? sl[qi][bq] : sl[qi][a];
            int smn = sw ? sl[qi][a]  : sl[qi][bq];
            sl[qi][a] = smx; sl[qi][bq] = smn;
        }
    }
#pragma unroll
    for (int qi = 0; qi < 2; qi++) {
        int row = w * 2 + qi;
#pragma unroll
        for (int j = 0; j < 16; j++) dist[row][j * 64 + lane] = d[qi][j];
        unsigned int pk0 = 0, pk1 = 0;
#pragma unroll
        for (int j = 0; j < 8; j++) pk0 |= (unsigned)sl[qi][j] << (4 * j);
#pragma unroll
        for (int j = 0; j < 8; j++) pk1 |= (unsigned)sl[qi][8 + j] << (4 * j);
        *(unsigned int*)&slotpk[row][lane * 8]     = pk0;
        *(unsigned int*)&slotpk[row][lane * 8 + 4] = pk1;
    }
    float head[2] = {d[0][0], d[1][0]};
    int ptr[2] = {0, 0};
    for (int t = 0; t < KNNK; t++) {
#pragma unroll
        for (int qi = 0; qi < 2; qi++) {
            int row = w * 2 + qi;
            float bv = head[qi];
#pragma unroll
            for (int s = 1; s < 64; s <<= 1) bv = fmaxf(bv, __shfl_xor(bv, s));
            unsigned long long ball = __ballot(head[qi] == bv);
            int wl = (int)__builtin_ctzll(ball);
            if (lane == wl) {
                int pp = ptr[qi];
                int slot = (slotpk[row][lane * 8 + (pp >> 1)] >> (4 * (pp & 1))) & 15;
                idxout[(q0 + row) * KNNK + t] = slot * 64 + lane;
                pp++;
                ptr[qi] = pp;
                int a = (pp < 16 ? pp : 15) * 64 + lane;
                float nv = dist[row][a];
                head[qi] = (pp < 16) ? nv : -INFINITY;
            }
        }
    }
}

// r1 zeroing helper (done by one designated block of the kernel preceding the gather)
__device__ __forceinline__ void zero_r1(float* r1s, float* r1q, int O, int tid) {
    for (int i = tid; i < 32 * O; i += 256) { r1s[i] = 0.f; r1q[i] = 0.f; }
}

// ---------------- fused kNN stage 1 (C=3) + stage-1 z-gemm, 8 queries/block ----------------
__global__ __launch_bounds__(256, 4) void knn3_fused(const float* __restrict__ x,
                                                     const float* __restrict__ w1,
                                                     float* __restrict__ zf,
                                                     int* __restrict__ idxout,
                                                     float* __restrict__ r1s, float* __restrict__ r1q) {
    __shared__ float dist[8][1024];
    __shared__ __align__(8) unsigned char slotpk[8][512];
    int tid = threadIdx.x;
    int q0 = (blockIdx.x & 7) * 1024 + (blockIdx.x >> 3) * 8;   // XCD swizzle
    int b = q0 >> 10;
    if (blockIdx.x == 0) zero_r1(r1s, r1q, 64, tid);
    const float* xb = x + (size_t)b * NN * 3;
    int lane = tid & 63, w = tid >> 6;
    float qx[8], qy[8], qz[8];
#pragma unroll
    for (int q = 0; q < 8; q++) {
        const float* qr = xb + (size_t)((q0 & (NN - 1)) + q) * 3;
        qx[q] = qr[0]; qy[q] = qr[1]; qz[q] = qr[2];
    }
#pragma unroll
    for (int cq = 0; cq < 4; cq++) {
        int cand = w * 256 + cq * 64 + lane;
        const float* cr = xb + (size_t)cand * 3;
        float cx = cr[0], cy = cr[1], cz = cr[2];
        float sqc = 0.f;
        sqc += cx * cx; sqc += cy * cy; sqc += cz * cz;
#pragma unroll
        for (int q = 0; q < 8; q++) {
            float d = qx[q] * cx + qy[q] * cy + qz[q] * cz;
            dist[q][cand] = 2.f * d - sqc;
        }
    }
    for (int i = tid; i < 8 * 128; i += 256) {
        int lq = i >> 7, j = i & 127;
        const float* wr = w1 + (j < 64 ? j * 6 : (j - 64) * 6 + 3);
        const float* xr = x + (size_t)(q0 + lq) * 3;
        zf[(size_t)(q0 + lq) * 128 + j] = wr[0] * xr[0] + wr[1] * xr[1] + wr[2] * xr[2];
    }
    __syncthreads();
    select20_srt(dist, slotpk, q0, w, lane, idxout);
}

// ---------------- knn core (stages 2-4), packed-fp32 dist + sort-select ----------------
template<int C>
__device__ __forceinline__ void knn_body(const float* __restrict__ xT,
                                         const float* __restrict__ xt, int off,
                                         const float* __restrict__ sqn,
                                         int* __restrict__ idxout,
                                         float (*dist)[1024], unsigned char (*slotpk)[512],
                                         float* qsT_raw, int knnBlk) {
    float (*qsT)[8] = (float (*)[8])qsT_raw;
    int tid = threadIdx.x;
    int q0 = (knnBlk & 7) * 1024 + (knnBlk >> 3) * 8;           // XCD swizzle
    int b = q0 >> 10;
    const float* xb = xt + (size_t)b * NN * LDC + off;
    for (int j = tid; j < 2 * C; j += 256) {
        int c = j % C, ph = j / C;
        int pb = (q0 & (NN - 1)) + ph * 4;
        float4 v;
        v.x = xb[(size_t)(pb + 0) * LDC + c];
        v.y = xb[(size_t)(pb + 1) * LDC + c];
        v.z = xb[(size_t)(pb + 2) * LDC + c];
        v.w = xb[(size_t)(pb + 3) * LDC + c];
        *(float4*)&qsT[c][ph * 4] = v;
    }
    __syncthreads();
    int lane = tid & 63, w = tid >> 6;
    int cand0 = w * 256 + 4 * lane;
    const float* xTb = xT + (size_t)b * C * 1024;
    float4 sq4 = *(const float4*)(sqn + b * NN + cand0);
    v2f acc2[4][4];
#pragma unroll
    for (int j = 0; j < 4; j++)
#pragma unroll
        for (int p = 0; p < 4; p++) acc2[j][p] = (v2f){0.f, 0.f};
    for (int cg = 0; cg < C / 4; cg++) {
        float4 rch[4];
#pragma unroll
        for (int c = 0; c < 4; c++)
            rch[c] = *(const float4*)(xTb + (size_t)(4 * cg + c) * 1024 + cand0);
#pragma unroll
        for (int c = 0; c < 4; c++) {
            float4 qa = *(const float4*)&qsT[4 * cg + c][0];
            float4 qb = *(const float4*)&qsT[4 * cg + c][4];
            v2f qp[4] = {{qa.x, qa.y}, {qa.z, qa.w}, {qb.x, qb.y}, {qb.z, qb.w}};
            float rj[4] = {rch[c].x, rch[c].y, rch[c].z, rch[c].w};
#pragma unroll
            for (int j = 0; j < 4; j++) {
                v2f rr = {rj[j], rj[j]};
                acc2[j][0] += rr * qp[0];
                acc2[j][1] += rr * qp[1];
                acc2[j][2] += rr * qp[2];
                acc2[j][3] += rr * qp[3];
            }
        }
    }
#pragma unroll
    for (int p = 0; p < 4; p++)
#pragma unroll
        for (int half = 0; half < 2; half++) {
            int q = 2 * p + half;
            float4 dv;
            dv.x = 2.f * acc2[0][p][half] - sq4.x;
            dv.y = 2.f * acc2[1][p][half] - sq4.y;
            dv.z = 2.f * acc2[2][p][half] - sq4.z;
            dv.w = 2.f * acc2[3][p][half] - sq4.w;
            *(float4*)&dist[q][cand0] = dv;
        }
    __syncthreads();
    select20_srt(dist, slotpk, q0, w, lane, idxout);
}

// ---------------- FAT kernel stages 2-3: knn (blocks<1024) + zgemm (blocks>=1024) ----------------
template<int C, int ZO2>
__global__ __launch_bounds__(256, 4) void knnz_fat(const float* __restrict__ xT,
                                                   const float* __restrict__ xt, int off,
                                                   const float* __restrict__ sqn,
                                                   int* __restrict__ idxout,
                                                   const float* __restrict__ w,
                                                   float* __restrict__ zf,
                                                   float* __restrict__ r1s, float* __restrict__ r1q,
                                                   int Onext) {
    __shared__ float dist[8][1024];
    __shared__ __align__(8) unsigned char slotpk[8][512];
    __shared__ __align__(16) float qsT_raw[C * 8];
    int tid = threadIdx.x;
    if ((int)blockIdx.x < BB * NN / 8) {
        knn_body<C>(xT, xt, off, sqn, idxout, dist, slotpk, qsT_raw, blockIdx.x);
        return;
    }
    // ---- zgemm path ----
    constexpr int ZO = ZO2 / 2;
    int zblk = blockIdx.x - BB * NN / 8;
    if (zblk == 0) zero_r1(r1s, r1q, Onext, tid);
    float (*xs)[C] = (float (*)[C])&dist[0][0];
    int p0 = zblk * 16;
    for (int j = tid; j < 16 * (C / 4); j += 256) {
        int p = j / (C / 4), c4 = j % (C / 4);
        *(float4*)&xs[p][4 * c4] = *(const float4*)(xt + (size_t)(p0 + p) * LDC + off + 4 * c4);
    }
    __syncthreads();
    for (int j = tid; j < ZO2; j += 256) {
        const float* wr = w + (j < ZO ? (size_t)j * 2 * C : (size_t)(j - ZO) * 2 * C + C);
        float acc[16];
#pragma unroll
        for (int p = 0; p < 16; p++) acc[p] = 0.f;
        for (int c4 = 0; c4 < C / 4; c4++) {
            float4 wv = *(const float4*)(wr + 4 * c4);
#pragma unroll
            for (int p = 0; p < 16; p++) {
                float4 xv = *(const float4*)&xs[p][4 * c4];
                acc[p] += wv.x * xv.x + wv.y * xv.y + wv.z * xv.z + wv.w * xv.w;
            }
        }
#pragma unroll
        for (int p = 0; p < 16; p++) zf[(size_t)(p0 + p) * ZO2 + j] = acc[p];
    }
}

// ---------------- stage-4 knn (separate; zeroes r1 for stage 4) ----------------
template<int C>
__global__ __launch_bounds__(256, 4) void knn_fused(const float* __restrict__ xT,
                                                    const float* __restrict__ xt, int off,
                                                    const float* __restrict__ sqn,
                                                    int* __restrict__ idxout,
                                                    float* __restrict__ r1s, float* __restrict__ r1q,
                                                    int Onext) {
    __shared__ float dist[8][1024];
    __shared__ __align__(8) unsigned char slotpk[8][512];
    __shared__ __align__(16) float qsT_raw[C * 8];
    if (blockIdx.x == 0) zero_r1(r1s, r1q, Onext, threadIdx.x);
    knn_body<C>(xT, xt, off, sqn, idxout, dist, slotpk, qsT_raw, blockIdx.x);
}

// ---------------- stage-4 z-gemm: bf16 MFMA, bf16 output ----------------
__global__ __launch_bounds__(256) void zgemm4_mfma(const float* __restrict__ xtcat,
                                                   const float* __restrict__ w4,
                                                   __hip_bfloat16* __restrict__ zf4) {
    __shared__ __hip_bfloat16 A[128][72];
    __shared__ __hip_bfloat16 W[128][72];
    int mt = blockIdx.x >> 2, nt = blockIdx.x & 3;
    int tid = threadIdx.x;
    int lane = tid & 63, wvx = tid >> 6;
    int mw = wvx >> 1, nw = wvx & 1;
    int m0 = lane & 15, qd = lane >> 4;
    int r = tid & 127, hf = tid >> 7;
    facc4 acc[4][4];
    facc4 zz = {0.f, 0.f, 0.f, 0.f};
#pragma unroll
    for (int mi = 0; mi < 4; mi++)
#pragma unroll
        for (int ni = 0; ni < 4; ni++) acc[mi][ni] = zz;
    int j = nt * 128 + r;
    const float* wsrc = w4 + (j < 256 ? (size_t)j * 256 : (size_t)(j - 256) * 256 + 128);
    const float* asrc = xtcat + (size_t)(mt * 128 + r) * 512 + 128;
    for (int kc = 0; kc < 2; kc++) {
#pragma unroll
        for (int u = 0; u < 4; u++) {
            int c0 = kc * 64 + hf * 32 + 8 * u;
            float4 a0 = *(const float4*)(asrc + c0);
            float4 a1 = *(const float4*)(asrc + c0 + 4);
            *(bh8*)&A[r][hf * 32 + 8 * u] = cvt8(a0, a1);
            float4 w0 = *(const float4*)(wsrc + c0);
            float4 w1 = *(const float4*)(wsrc + c0 + 4);
            *(bh8*)&W[r][hf * 32 + 8 * u] = cvt8(w0, w1);
        }
        __syncthreads();
#pragma unroll
        for (int kk = 0; kk < 2; kk++) {
            bfrag8 af[4], bf[4];
#pragma unroll
            for (int mi = 0; mi < 4; mi++)
                af[mi] = *(const bfrag8*)&A[64 * mw + 16 * mi + m0][32 * kk + 8 * qd];
#pragma unroll
            for (int ni = 0; ni < 4; ni++)
                bf[ni] = *(const bfrag8*)&W[64 * nw + 16 * ni + m0][32 * kk + 8 * qd];
#pragma unroll
            for (int mi = 0; mi < 4; mi++)
#pragma unroll
                for (int ni = 0; ni < 4; ni++)
                    acc[mi][ni] = __builtin_amdgcn_mfma_f32_16x16x32_bf16(af[mi], bf[ni], acc[mi][ni], 0, 0, 0);
        }
        __syncthreads();
    }
#pragma unroll
    for (int mi = 0; mi < 4; mi++)
#pragma unroll
        for (int ni = 0; ni < 4; ni++)
#pragma unroll
            for (int rg = 0; rg < 4; rg++) {
                int row = mt * 128 + mw * 64 + mi * 16 + qd * 4 + rg;
                int col = nt * 128 + nw * 64 + ni * 16 + m0;
                zf4[(size_t)row * 512 + col] = __float2bfloat16(acc[mi][ni][rg]);
            }
}

// ---------------- gather + stats (fp32 zf, stages 1-3): in-block reduce + atomics ----------------
template<int O2>
__global__ __launch_bounds__(256) void gatherstats_k(const float* __restrict__ zf,
                                                     const int* __restrict__ idx,
                                                     float* __restrict__ ymax, float* __restrict__ ymin,
                                                     float* __restrict__ r1s, float* __restrict__ r1q) {
    constexpr int O = O2 / 2;
    __shared__ float red_s[4][O], red_q[4][O];
    int wv = threadIdx.x >> 6, lane = threadIdx.x & 63;
    int n = (blockIdx.x & 7) * 1024 + (blockIdx.x >> 3) * 4 + wv;   // XCD swizzle
    int b = n >> 10;
    const float* zbatch = zf + (size_t)b * NN * O2;
    int nb[KNNK];
#pragma unroll
    for (int k = 0; k < KNNK; k++) nb[k] = idx[n * KNNK + k];
#pragma unroll
    for (int ch = 0; ch < O / 64; ch++) {
        int o = ch * 64 + lane;
        float g[KNNK];
#pragma unroll
        for (int k = 0; k < KNNK; k++) g[k] = zbatch[(size_t)nb[k] * O2 + o];
        float mx = -INFINITY, mn = INFINITY, s = 0.f, ss = 0.f;
#pragma unroll
        for (int k = 0; k < KNNK; k++) {
            float v = g[k];
            mx = fmaxf(mx, v); mn = fminf(mn, v); s += v; ss += v * v;
        }
        float zn  = zf[(size_t)n * O2 + o];
        float zbn = zf[(size_t)n * O2 + O + o];
        float d = zbn - zn;
        mx += d; mn += d;
        ss = ss + 2.f * d * s + (float)KNNK * d * d;
        s  = s + (float)KNNK * d;
        ymax[(size_t)n * O + o] = mx;
        ymin[(size_t)n * O + o] = mn;
        red_s[wv][o] = s;
        red_q[wv][o] = ss;
    }
    __syncthreads();
    int bucket = blockIdx.x & 31;
    for (int o = threadIdx.x; o < O; o += 256) {
        float s4 = red_s[0][o] + red_s[1][o] + red_s[2][o] + red_s[3][o];
        float q4 = red_q[0][o] + red_q[1][o] + red_q[2][o] + red_q[3][o];
        atomicAdd(&r1s[(size_t)bucket * O + o], s4);
        atomicAdd(&r1q[(size_t)bucket * O + o], q4);
    }
}

// ---------------- gather + stats, bf16 zf4 (stage 4) ----------------
__global__ __launch_bounds__(256) void gatherstats4_k(const __hip_bfloat16* __restrict__ zf4,
                                                      const int* __restrict__ idx,
                                                      float* __restrict__ ymax, float* __restrict__ ymin,
                                                      float* __restrict__ r1s, float* __restrict__ r1q) {
    __shared__ float red_s[4][256], red_q[4][256];
    int wv = threadIdx.x >> 6, lane = threadIdx.x & 63;
    int n = (blockIdx.x & 7) * 1024 + (blockIdx.x >> 3) * 4 + wv;
    int b = n >> 10;
    const __hip_bfloat16* zbatch = zf4 + (size_t)b * NN * 512;
    int nb[KNNK];
#pragma unroll
    for (int k = 0; k < KNNK; k++) nb[k] = idx[n * KNNK + k];
#pragma unroll
    for (int ch = 0; ch < 4; ch++) {
        int o = ch * 64 + lane;
        float g[KNNK];
#pragma unroll
        for (int k = 0; k < KNNK; k++) g[k] = __bfloat162float(zbatch[(size_t)nb[k] * 512 + o]);
        float mx = -INFINITY, mn = INFINITY, s = 0.f, ss = 0.f;
#pragma unroll
        for (int k = 0; k < KNNK; k++) {
            float v = g[k];
            mx = fmaxf(mx, v); mn = fminf(mn, v); s += v; ss += v * v;
        }
        float zn  = __bfloat162float(zf4[(size_t)n * 512 + o]);
        float zbn = __bfloat162float(zf4[(size_t)n * 512 + 256 + o]);
        float d = zbn - zn;
        mx += d; mn += d;
        ss = ss + 2.f * d * s + (float)KNNK * d * d;
        s  = s + (float)KNNK * d;
        ymax[(size_t)n * 256 + o] = mx;
        ymin[(size_t)n * 256 + o] = mn;
        red_s[wv][o] = s;
        red_q[wv][o] = ss;
    }
    __syncthreads();
    int bucket = blockIdx.x & 31;
    for (int o = threadIdx.x; o < 256; o += 256) {
        float s4 = red_s[0][o] + red_s[1][o] + red_s[2][o] + red_s[3][o];
        float q4 = red_q[0][o] + red_q[1][o] + red_q[2][o] + red_q[3][o];
        atomicAdd(&r1s[(size_t)bucket * 256 + o], s4);
        atomicAdd(&r1q[(size_t)bucket * 256 + o], q4);
    }
}

// ---------------- BN+lrelu epilogue + transpose + |c|^2 + bf16 copy, s/t computed in-block ----------------
template<int O>
__global__ __launch_bounds__(256) void epitrans2_k(const float* __restrict__ ymax, const float* __restrict__ ymin,
                                                   const float* __restrict__ r1s, const float* __restrict__ r1q,
                                                   const float* __restrict__ g, const float* __restrict__ beta,
                                                   double invM,
                                                   float* __restrict__ xtcat, int off_out,
                                                   float* __restrict__ xT, float* __restrict__ sqn,
                                                   __hip_bfloat16* __restrict__ xbf) {
    __shared__ float tile[64][O + 1];
    __shared__ float ssh[O], tth[O];
    int n0 = blockIdx.x * 64;
    int b = n0 >> 10;
    int tid = threadIdx.x;
    for (int o = tid; o < O; o += 256) {
        double sd = 0.0, qd = 0.0;
        for (int r = 0; r < 32; r++) { sd += r1s[(size_t)r * O + o]; qd += r1q[(size_t)r * O + o]; }
        double mean = sd * invM;
        double var = qd * invM - mean * mean;
        float inv = (float)(1.0 / sqrt(var + 1e-5));
        float sc = g[o] * inv;
        ssh[o] = sc;
        tth[o] = beta[o] - (float)mean * sc;
    }
    __syncthreads();
    for (int i = tid; i < 64 * O; i += 256) {
        int nl = i / O;
        int o = i & (O - 1);
        int n = n0 + nl;
        float sc = ssh[o];
        float v = sc >= 0.f ? ymax[(size_t)n * O + o] : ymin[(size_t)n * O + o];
        float y = sc * v + tth[o];
        y = y >= 0.f ? y : 0.2f * y;
        xtcat[(size_t)n * LDC + off_out + o] = y;
        xbf[(size_t)n * LDC + off_out + o] = __float2bfloat16(y);
        tile[nl][o] = y;
    }
    __syncthreads();
    if (tid < 64) {
        float sq = 0.f;
        for (int c = 0; c < O; c++) { float v = tile[tid][c]; sq += v * v; }
        sqn[n0 + tid] = sq;
    }
    int r = tid >> 4, cq = tid & 15;
#pragma unroll
    for (int ct = 0; ct < O / 16; ct++) {
        int c = ct * 16 + r;
        float4 ov;
        ov.x = tile[4 * cq + 0][c];
        ov.y = tile[4 * cq + 1][c];
        ov.z = tile[4 * cq + 2][c];
        ov.w = tile[4 * cq + 3][c];
        *(float4*)(xT + ((size_t)b * O + c) * 1024 + (n0 & (NN - 1)) + 4 * cq) = ov;
    }
}

// ---------------- stage-4 epilogue: s/t in-block, writes xbf ONLY ----------------
__global__ __launch_bounds__(256) void epilogue4_k(const float* __restrict__ ymax, const float* __restrict__ ymin,
                                                   const float* __restrict__ r1s, const float* __restrict__ r1q,
                                                   const float* __restrict__ g, const float* __restrict__ beta,
                                                   double invM,
                                                   __hip_bfloat16* __restrict__ xbf) {
    __shared__ float ssh[256], tth[256];
    int n0 = blockIdx.x * 64;
    int tid = threadIdx.x;
    {
        int o = tid;
        double sd = 0.0, qd = 0.0;
        for (int r = 0; r < 32; r++) { sd += r1s[(size_t)r * 256 + o]; qd += r1q[(size_t)r * 256 + o]; }
        double mean = sd * invM;
        double var = qd * invM - mean * mean;
        float inv = (float)(1.0 / sqrt(var + 1e-5));
        float sc = g[o] * inv;
        ssh[o] = sc;
        tth[o] = beta[o] - (float)mean * sc;
    }
    __syncthreads();
    for (int i = tid; i < 64 * 256; i += 256) {
        int nl = i >> 8;
        int o = i & 255;
        int n = n0 + nl;
        float sc = ssh[o];
        float v = sc >= 0.f ? ymax[(size_t)n * 256 + o] : ymin[(size_t)n * 256 + o];
        float y = sc * v + tth[o];
        y = y >= 0.f ? y : 0.2f * y;
        xbf[(size_t)n * LDC + 256 + o] = __float2bfloat16(y);
    }
}

// ---------------- stage 5: bf16 MFMA GEMM (W staged from fp32 w5) w/ fused stats ----------------
__global__ __launch_bounds__(256) void gemm5_mfma(const __hip_bfloat16* __restrict__ xbf,
                                                  const float* __restrict__ w5,
                                                  float* __restrict__ pmax, float* __restrict__ pmn,
                                                  float* __restrict__ ps, float* __restrict__ pq) {
    __shared__ __hip_bfloat16 A[128][72];
    __shared__ __hip_bfloat16 W[128][72];
    int mt = blockIdx.x >> 2, nt = blockIdx.x & 3;
    int tid = threadIdx.x;
    int lane = tid & 63, wvx = tid >> 6;
    int mw = wvx >> 1, nw = wvx & 1;
    int m0 = lane & 15, qd = lane >> 4;
    int r = tid & 127, hf = tid >> 7;
    facc4 acc[4][4];
    facc4 zz = {0.f, 0.f, 0.f, 0.f};
#pragma unroll
    for (int mi = 0; mi < 4; mi++)
#pragma unroll
        for (int ni = 0; ni < 4; ni++) acc[mi][ni] = zz;
    for (int kc = 0; kc < 8; kc++) {
        const __hip_bfloat16* ap = xbf + (size_t)(mt * 128 + r) * 512 + kc * 64 + hf * 32;
        const float* wp = w5 + (size_t)(nt * 128 + r) * 512 + kc * 64 + hf * 32;
#pragma unroll
        for (int u = 0; u < 4; u++) {
            bh8 av = *(const bh8*)(ap + 8 * u);
            *(bh8*)&A[r][hf * 32 + 8 * u] = av;
            float4 w0 = *(const float4*)(wp + 8 * u);
            float4 w1 = *(const float4*)(wp + 8 * u + 4);
            *(bh8*)&W[r][hf * 32 + 8 * u] = cvt8(w0, w1);
        }
        __syncthreads();
#pragma unroll
        for (int kk = 0; kk < 2; kk++) {
            bfrag8 af[4], bf[4];
#pragma unroll
            for (int mi = 0; mi < 4; mi++)
                af[mi] = *(const bfrag8*)&A[64 * mw + 16 * mi + m0][32 * kk + 8 * qd];
#pragma unroll
            for (int ni = 0; ni < 4; ni++)
                bf[ni] = *(const bfrag8*)&W[64 * nw + 16 * ni + m0][32 * kk + 8 * qd];
#pragma unroll
            for (int mi = 0; mi < 4; mi++)
#pragma unroll
                for (int ni = 0; ni < 4; ni++)
                    acc[mi][ni] = __builtin_amdgcn_mfma_f32_16x16x32_bf16(af[mi], bf[ni], acc[mi][ni], 0, 0, 0);
        }
        __syncthreads();
    }
#pragma unroll
    for (int mi = 0; mi < 4; mi++) {
        int grp = mt * 8 + mw * 4 + mi;
#pragma unroll
        for (int ni = 0; ni < 4; ni++) {
            float mx = -INFINITY, mn = INFINITY, s = 0.f, ss = 0.f;
#pragma unroll
            for (int rg = 0; rg < 4; rg++) {
                float v = acc[mi][ni][rg];
                mx = fmaxf(mx, v); mn = fminf(mn, v); s += v; ss += v * v;
            }
#pragma unroll
            for (int m = 16; m < 64; m <<= 1) {
                mx = fmaxf(mx, __shfl_xor(mx, m));
                mn = fminf(mn, __shfl_xor(mn, m));
                s += __shfl_xor(s, m);
                ss += __shfl_xor(ss, m);
            }
            if (qd == 0) {
                int o = nt * 128 + nw * 64 + ni * 16 + m0;
                pmax[(size_t)grp * 512 + o] = mx;
                pmn [(size_t)grp * 512 + o] = mn;
                ps  [(size_t)grp * 512 + o] = s;
                pq  [(size_t)grp * 512 + o] = ss;
            }
        }
    }
}

// ---------------- stage-5 BN stats (separate kernel: coalesced 8-block reduce) ----------------
__global__ __launch_bounds__(256) void bnstat5_k(const float* __restrict__ ps, const float* __restrict__ pq,
                                                 const float* __restrict__ g, const float* __restrict__ beta,
                                                 float* __restrict__ s_out, float* __restrict__ t_out) {
    __shared__ double lds_s[4][64], lds_q[4][64];
    int lane = threadIdx.x & 63, wv = threadIdx.x >> 6;
    int o = blockIdx.x * 64 + lane;
    double s = 0.0, q = 0.0;
    for (int r = wv; r < 512; r += 4) {
        s += ps[(size_t)r * 512 + o];
        q += pq[(size_t)r * 512 + o];
    }
    lds_s[wv][lane] = s; lds_q[wv][lane] = q;
    __syncthreads();
    if (wv == 0) {
        s = lds_s[0][lane] + lds_s[1][lane] + lds_s[2][lane] + lds_s[3][lane];
        q = lds_q[0][lane] + lds_q[1][lane] + lds_q[2][lane] + lds_q[3][lane];
        double invM = 1.0 / (BB * NN);
        double mean = s * invM;
        double var = q * invM - mean * mean;
        float inv = (float)(1.0 / sqrt(var + 1e-5));
        float sc = g[o] * inv;
        s_out[o] = sc;
        t_out[o] = beta[o] - (float)mean * sc;
    }
}

// ---------------- per-batch max/min reduce + BN + lrelu + feat @ wemb^T ----------------
__global__ __launch_bounds__(256) void featgemm_k(const float* __restrict__ pmax, const float* __restrict__ pmn,
                                                  const float* __restrict__ s, const float* __restrict__ t,
                                                  const float* __restrict__ wemb, float* __restrict__ out) {
    __shared__ __align__(16) float feat[512];
    int b = blockIdx.x, tid = threadIdx.x;
    for (int o = tid; o < 512; o += 256) {
        float mx = -INFINITY, mn = INFINITY;
        for (int r = b * 64; r < (b + 1) * 64; r++) {
            mx = fmaxf(mx, pmax[(size_t)r * 512 + o]);
            mn = fminf(mn, pmn [(size_t)r * 512 + o]);
        }
        float sc = s[o];
        float v = sc >= 0.f ? mx : mn;
        float y = sc * v + t[o];
        feat[o] = y >= 0.f ? y : 0.2f * y;
    }
    __syncthreads();
    const float4* wr = (const float4*)(wemb + (size_t)tid * 512);
    float acc = 0.f;
    for (int c4 = 0; c4 < 128; c4++) {
        float4 wv = wr[c4];
        float4 fv = *(const float4*)&feat[c4 * 4];
        acc += wv.x * fv.x + wv.y * fv.y + wv.z * fv.z + wv.w * fv.w;
    }
    out[(size_t)b * 256 + tid] = acc;
}

extern "C" void kernel_launch(void* const* d_in, const int* in_sizes, int n_in,
                              void* d_out, int out_size, void* d_ws, size_t ws_size,
                              hipStream_t stream) {
    const float* x    = (const float*)d_in[0];
    const float* w1   = (const float*)d_in[1];
    const float* g1   = (const float*)d_in[2];
    const float* b1   = (const float*)d_in[3];
    const float* w2   = (const float*)d_in[4];
    const float* g2   = (const float*)d_in[5];
    const float* b2   = (const float*)d_in[6];
    const float* w3   = (const float*)d_in[7];
    const float* g3   = (const float*)d_in[8];
    const float* b3   = (const float*)d_in[9];
    const float* w4   = (const float*)d_in[10];
    const float* g4   = (const float*)d_in[11];
    const float* b4   = (const float*)d_in[12];
    const float* w5   = (const float*)d_in[13];
    const float* g5   = (const float*)d_in[14];
    const float* b5   = (const float*)d_in[15];
    const float* wemb = (const float*)d_in[16];
    float* out = (float*)d_out;

    float* fws    = (float*)d_ws;
    float* xtcat  = fws;                                 // 4,194,304
    float* ymax   = xtcat + (size_t)BB * NN * 512;       // 2,097,152
    float* ymin   = ymax + (size_t)BB * NN * 256;        // 2,097,152
    float* psum   = ymin + (size_t)BB * NN * 256;        // 2,097,152 (xT alias)
    float* psumsq = psum + (size_t)BB * NN * 256;        // 2,097,152 (spare)
    float* xT     = psum;                                // alias
    float* pmax   = ymax;                                // alias: stage-5 partials
    float* pmn    = pmax + 512 * 512;
    float* ps5    = pmn + 512 * 512;
    float* pq5    = ps5 + 512 * 512;
    float* sqn    = psumsq + (size_t)BB * NN * 256;      // 8192
    float* s_arr  = sqn + BB * NN;                       // 512
    float* t_arr  = s_arr + 512;                         // 512
    float* r1s    = t_arr + 512;                         // 32*512
    float* r1q    = r1s + 32 * 512;                      // 32*512
    int*   idxb   = (int*)(r1q + 32 * 512);              // 8192*20 ints
    float* zfull  = (float*)(idxb + BB * NN * KNNK);     // 8192*512 fp32 (stages 1-3)
    __hip_bfloat16* zf4 = (__hip_bfloat16*)zfull;        // alias: stage-4 z, bf16
    __hip_bfloat16* xbf = (__hip_bfloat16*)(zfull + (size_t)BB * NN * 512);   // 8192*512 bf16

    const double invM_edge = 1.0 / ((double)BB * NN * KNNK);
    const int nbn = BB * NN;
    const int NK = nbn / 8;       // 1024 knn blocks (8 queries each)
    const int NZ = nbn / 16;      // 512 zgemm blocks

    // ---- Stage 1 ----
    knn3_fused<<<NK, 256, 0, stream>>>(x, w1, zfull, idxb, r1s, r1q);
    gatherstats_k<128><<<nbn / 4, 256, 0, stream>>>(zfull, idxb, ymax, ymin, r1s, r1q);
    epitrans2_k<64><<<128, 256, 0, stream>>>(ymax, ymin, r1s, r1q, g1, b1, invM_edge, xtcat, 0, xT, sqn, xbf);

    // ---- Stage 2 ----
    knnz_fat<64, 128><<<NK + NZ, 256, 0, stream>>>(xT, xtcat, 0, sqn, idxb, w2, zfull, r1s, r1q, 64);
    gatherstats_k<128><<<nbn / 4, 256, 0, stream>>>(zfull, idxb, ymax, ymin, r1s, r1q);
    epitrans2_k<64><<<128, 256, 0, stream>>>(ymax, ymin, r1s, r1q, g2, b2, invM_edge, xtcat, 64, xT, sqn, xbf);

    // ---- Stage 3 ----
    knnz_fat<64, 256><<<NK + NZ, 256, 0, stream>>>(xT, xtcat, 64, sqn, idxb, w3, zfull, r1s, r1q, 128);
    gatherstats_k<256><<<nbn / 4, 256, 0, stream>>>(zfull, idxb, ymax, ymin, r1s, r1q);
    epitrans2_k<128><<<128, 256, 0, stream>>>(ymax, ymin, r1s, r1q, g3, b3, invM_edge, xtcat, 128, xT, sqn, xbf);

    // ---- Stage 4 ----
    knn_fused<128><<<NK, 256, 0, stream>>>(xT, xtcat, 128, sqn, idxb, r1s, r1q, 256);
    zgemm4_mfma<<<256, 256, 0, stream>>>(xtcat, w4, zf4);
    gatherstats4_k<<<nbn / 4, 256, 0, stream>>>(zf4, idxb, ymax, ymin, r1s, r1q);
    epilogue4_k<<<128, 256, 0, stream>>>(ymax, ymin, r1s, r1q, g4, b4, invM_edge, xbf);

    // ---- Stage 5 ----
    gemm5_mfma<<<256, 256, 0, stream>>>(xbf, w5, pmax, pmn, ps5, pq5);
    bnstat5_k<<<8, 256, 0, stream>>>(ps5, pq5, g5, b5, s_arr, t_arr);
    featgemm_k<<<BB, 256, 0, stream>>>(pmax, pmn, s_arr, t_arr, wemb, out);
}